// Round 6
// baseline (151.486 us; speedup 1.0000x reference)
//
#include <hip/hip_runtime.h>
#include <cstddef>

// Problem constants
constexpr int Bn  = 16;    // batch
constexpr int CIc = 32;    // in channels
constexpr int COc = 32;    // out channels
constexpr int Kc  = 16;    // kernel width
constexpr int IN  = 8192;  // input length
constexpr int OUTL = 8176; // output length = IN - K

// Tiling
constexpr int O_B  = 16;   // o-positions per block (8176/16 = 511 exact)
constexpr int CCH  = 8;    // channels staged per chunk
constexpr int NPOS = 32;   // staged x positions (max access o0+31 <= 8191: in bounds)
constexpr int BST  = 18;   // row stride in floats: 8 rows x 2 bg spread 2-way over banks (free)
constexpr int NCHUNK = CIc / CCH;  // 4

__global__ __launch_bounds__(256, 2)
void conv1d_cppn_kernel(const float* __restrict__ x, const float* __restrict__ w,
                        const float* __restrict__ bias, float* __restrict__ out) {
    // x transposed: xs[cc][pos][b]  (18,432 B)
    __shared__ float xs[CCH][NPOS][BST];

    const int tid = threadIdx.x;
    const int bg  = tid & 1;          // batch half: b in [bg*8, bg*8+8)
    const int ogp = (tid >> 1) & 7;   // o-pair index: owns o, o+1
    const int dg  = tid >> 4;         // 16 d-groups x 2 d = all 32 d
    const int o0 = blockIdx.x * O_B;
    const int ob = ogp * 2;           // local o base
    const int o  = o0 + ob;
    const int dbase = dg * 2;
    const int bb = bg * 8;

    // Staging decomposition (float4 over p): thread -> (sp4, sb), channels cl0+2q
    const int sp4 = tid & 7;
    const int sb  = (tid >> 3) & 15;
    const int cl0 = tid >> 7;

    // acc[jd][oo][j]: 2 d x 2 o x 8 b = 32 regs
    float acc[2][2][8];
#pragma unroll
    for (int i = 0; i < 2; ++i)
#pragma unroll
        for (int j = 0; j < 2; ++j)
#pragma unroll
            for (int q = 0; q < 8; ++q) acc[i][j][q] = 0.f;

    for (int chunk = 0; chunk < NCHUNK; ++chunk) {
        const int c0 = chunk * CCH;
        __syncthreads();
        // Stage x[b, c0..c0+8, o0..o0+32) transposed. 4 float4 loads/thread.
#pragma unroll
        for (int q = 0; q < 4; ++q) {
            const int cl = cl0 + 2 * q;
            const float4 v = *reinterpret_cast<const float4*>(
                &x[((size_t)sb * CIc + (c0 + cl)) * IN + o0 + sp4 * 4]);
            float (*prow)[BST] = &xs[cl][sp4 * 4];
            prow[0][sb] = v.x; prow[1][sb] = v.y; prow[2][sb] = v.z; prow[3][sb] = v.w;
        }
        __syncthreads();

#pragma unroll 2
        for (int cc = 0; cc < CCH; ++cc) {
            const int c = c0 + cc;
            // Sliding x window: rows ob+k (A) and ob+k+1 (B), 8 b's each.
            float xwA[8], xwB[8];
            *reinterpret_cast<float4*>(&xwA[0]) = *reinterpret_cast<const float4*>(&xs[cc][ob][bb]);
            *reinterpret_cast<float4*>(&xwA[4]) = *reinterpret_cast<const float4*>(&xs[cc][ob][bb + 4]);
            *reinterpret_cast<float4*>(&xwB[0]) = *reinterpret_cast<const float4*>(&xs[cc][ob + 1][bb]);
            *reinterpret_cast<float4*>(&xwB[4]) = *reinterpret_cast<const float4*>(&xs[cc][ob + 1][bb + 4]);

#pragma unroll
            for (int half = 0; half < 2; ++half) {
                // w taps half*8..+8 for 2 d x 2 o: 32 live w regs
                float wv[2][2][8];
#pragma unroll
                for (int jd = 0; jd < 2; ++jd)
#pragma unroll
                    for (int oo = 0; oo < 2; ++oo) {
                        const float4* wp = reinterpret_cast<const float4*>(
                            w + (((size_t)(dbase + jd) * CIc + c) * OUTL + (o + oo)) * Kc
                              + half * 8);
                        const float4 a  = wp[0];
                        const float4 b4 = wp[1];
                        wv[jd][oo][0] = a.x;  wv[jd][oo][1] = a.y;
                        wv[jd][oo][2] = a.z;  wv[jd][oo][3] = a.w;
                        wv[jd][oo][4] = b4.x; wv[jd][oo][5] = b4.y;
                        wv[jd][oo][6] = b4.z; wv[jd][oo][7] = b4.w;
                    }
#pragma unroll
                for (int kk = 0; kk < 8; ++kk) {
                    const int k = half * 8 + kk;
#pragma unroll
                    for (int jd = 0; jd < 2; ++jd) {
                        const float wk0 = wv[jd][0][kk];
                        const float wk1 = wv[jd][1][kk];
#pragma unroll
                        for (int j = 0; j < 8; ++j) {
                            acc[jd][0][j] += wk0 * xwA[j];
                            acc[jd][1][j] += wk1 * xwB[j];
                        }
                    }
                    // Slide window: A <- B, B <- row ob+k+2 (skip load after last tap)
                    if (k < 15) {
#pragma unroll
                        for (int j = 0; j < 8; ++j) xwA[j] = xwB[j];
                        const int r = ob + k + 2;   // <= 31
                        *reinterpret_cast<float4*>(&xwB[0]) = *reinterpret_cast<const float4*>(&xs[cc][r][bb]);
                        *reinterpret_cast<float4*>(&xwB[4]) = *reinterpret_cast<const float4*>(&xs[cc][r][bb + 4]);
                    }
                }
            }
        }
    }

    // Epilogue: bias + relu; float2 over (o, o+1)
#pragma unroll
    for (int jd = 0; jd < 2; ++jd) {
        const float bv = bias[dbase + jd];
#pragma unroll
        for (int j = 0; j < 8; ++j) {
            float v0 = acc[jd][0][j] + bv;
            float v1 = acc[jd][1][j] + bv;
            float2 st = make_float2(v0 > 0.f ? v0 : 0.f, v1 > 0.f ? v1 : 0.f);
            *reinterpret_cast<float2*>(
                &out[((size_t)(bb + j) * COc + (dbase + jd)) * OUTL + o]) = st;
        }
    }
}

extern "C" void kernel_launch(void* const* d_in, const int* in_sizes, int n_in,
                              void* d_out, int out_size, void* d_ws, size_t ws_size,
                              hipStream_t stream) {
    const float* x    = (const float*)d_in[0];
    const float* w    = (const float*)d_in[1];
    const float* bias = (const float*)d_in[2];
    float* out        = (float*)d_out;

    dim3 grid(OUTL / O_B);  // 511
    dim3 block(256);
    hipLaunchKernelGGL(conv1d_cppn_kernel, grid, block, 0, stream, x, w, bias, out);
}